// Round 16
// baseline (105.827 us; speedup 1.0000x reference)
//
#include <hip/hip_runtime.h>
#include <hip/hip_bf16.h>
#include <math.h>

#define B_   16
#define C_   512
#define D_   256
#define K_   16
#define RD_  128
#define H_   8
#define HD_  32
#define FFN_ 1024
#define M_   (B_ * C_)   // 8192 rows

typedef __attribute__((ext_vector_type(8))) short bf16x8;
typedef __attribute__((ext_vector_type(4))) float f32x4;

typedef __attribute__((address_space(1))) const int ga_int;
typedef __attribute__((address_space(3))) int ls_int;

static __device__ __forceinline__ short f2bf(float v) {
    __hip_bfloat16 h = __float2bfloat16(v);
    return *(short*)&h;
}
static __device__ __forceinline__ float bf2f(short s) {
    __hip_bfloat16 h = *(__hip_bfloat16*)&s;
    return __bfloat162float(h);
}
static __device__ __forceinline__ float4 ld4bf(const short* p) {
    uint2 u = *(const uint2*)p;
    float4 r;
    r.x = __uint_as_float((u.x & 0xffffu) << 16);
    r.y = __uint_as_float(u.x & 0xffff0000u);
    r.z = __uint_as_float((u.y & 0xffffu) << 16);
    r.w = __uint_as_float(u.y & 0xffff0000u);
    return r;
}

// ---------------------------------------------------------------------------
// All fp32->bf16 conversions in ONE kernel. x emits HI+LO; wq/wk emit HI+LO.
// ---------------------------------------------------------------------------
#define N8_X    (M_ * D_ / 8)
#define N8_INW  (768 * D_ / 8)
#define N8_OUTW (D_ * D_ / 8)
#define N8_W1   (FFN_ * D_ / 8)
#define N8_W2   (D_ * FFN_ / 8)
#define N8_WQ   (RD_ * D_ / 8)
#define N8_ALL  (N8_X + N8_INW + N8_OUTW + N8_W1 + N8_W2 + 2 * N8_WQ)

__global__ __launch_bounds__(256) void convert_all_kernel(
    const float* __restrict__ x, const float* __restrict__ inw,
    const float* __restrict__ outw, const float* __restrict__ w1,
    const float* __restrict__ w2, const float* __restrict__ wq,
    const float* __restrict__ wk,
    short* __restrict__ xbf, short* __restrict__ xlo,
    short* __restrict__ inwbf, short* __restrict__ outwbf,
    short* __restrict__ w1bf, short* __restrict__ w2bf,
    short* __restrict__ wqh, short* __restrict__ wql,
    short* __restrict__ wkh, short* __restrict__ wkl)
{
    int i = blockIdx.x * 256 + threadIdx.x;
    if (i >= N8_ALL) return;

    const float* s; short* dh; short* dl = nullptr; int off;
    if      (i < N8_X)                    { s = x;    dh = xbf;    dl = xlo; off = i; }
    else if (i < N8_X + N8_INW)           { s = inw;  dh = inwbf;  off = i - N8_X; }
    else if (i < N8_X + N8_INW + N8_OUTW) { s = outw; dh = outwbf; off = i - N8_X - N8_INW; }
    else if (i < N8_X + N8_INW + N8_OUTW + N8_W1)
                                          { s = w1;   dh = w1bf;   off = i - N8_X - N8_INW - N8_OUTW; }
    else if (i < N8_X + N8_INW + N8_OUTW + N8_W1 + N8_W2)
                                          { s = w2;   dh = w2bf;   off = i - N8_X - N8_INW - N8_OUTW - N8_W1; }
    else if (i < N8_X + N8_INW + N8_OUTW + N8_W1 + N8_W2 + N8_WQ)
                                          { s = wq;   dh = wqh; dl = wql; off = i - N8_X - N8_INW - N8_OUTW - N8_W1 - N8_W2; }
    else                                  { s = wk;   dh = wkh; dl = wkl; off = i - N8_X - N8_INW - N8_OUTW - N8_W1 - N8_W2 - N8_WQ; }

    const float4* sp = (const float4*)s + (size_t)off * 2;
    float4 v0 = sp[0], v1 = sp[1];
    float f[8] = {v0.x, v0.y, v0.z, v0.w, v1.x, v1.y, v1.z, v1.w};
    short rh[8], rl[8];
    #pragma unroll
    for (int j = 0; j < 8; ++j) {
        rh[j] = f2bf(f[j]);
        rl[j] = f2bf(f[j] - bf2f(rh[j]));
    }
    *(bf16x8*)(dh + (size_t)off * 8) = *(bf16x8*)rh;
    if (dl) *(bf16x8*)(dl + (size_t)off * 8) = *(bf16x8*)rl;
}

// ---------------------------------------------------------------------------
// bf16 MFMA GEMM (standalone; used for MLP1). Double-buffered gload_lds.
// ---------------------------------------------------------------------------
template<int BM, int BN, int OUT_BF16, int ACT>
__global__ __launch_bounds__(256) void gemm_mfma(
    const short* __restrict__ A, const short* __restrict__ W,
    const float* __restrict__ bias, void* __restrict__ Cout,
    int M, int N, int Kd)
{
    __shared__ short As[2][BM * 32];
    __shared__ short Bs[2][BN * 32];
    const int tid  = threadIdx.x;
    const int wave = tid >> 6;
    const int lane = tid & 63;
    const int bm = blockIdx.y * BM;
    const int bn = blockIdx.x * BN;
    constexpr int MI = BM / 32;
    constexpr int NJ = BN / 32;
    const int wr = (wave >> 1) * (BM / 2);
    const int wc = (wave & 1) * (BN / 2);

    const int fr = lane & 15;
    const int fk = (lane >> 4) * 8;
    const int r0 = tid >> 2, ch = (tid & 3) * 8;

    f32x4 acc[MI][NJ];
    #pragma unroll
    for (int i = 0; i < MI; ++i)
        #pragma unroll
        for (int j = 0; j < NJ; ++j)
            acc[i][j] = (f32x4){0.f, 0.f, 0.f, 0.f};

    auto stage = [&](int buf, int k0) {
        #pragma unroll
        for (int i = 0; i < BM / 64; ++i)
            __builtin_amdgcn_global_load_lds(
                (ga_int*)&A[(size_t)(bm + r0 + i * 64) * Kd + k0 + ch],
                (ls_int*)&As[buf][(tid + i * 256) * 8], 16, 0, 0);
        #pragma unroll
        for (int j = 0; j < BN / 64; ++j)
            __builtin_amdgcn_global_load_lds(
                (ga_int*)&W[(size_t)(bn + r0 + j * 64) * Kd + k0 + ch],
                (ls_int*)&Bs[buf][(tid + j * 256) * 8], 16, 0, 0);
    };

    stage(0, 0);
    int cur = 0;

    for (int k0 = 0; k0 < Kd; k0 += 32) {
        __syncthreads();
        if (k0 + 32 < Kd) stage(cur ^ 1, k0 + 32);

        bf16x8 af[MI], bfr[NJ];
        #pragma unroll
        for (int i = 0; i < MI; ++i) af[i]  = *(bf16x8*)&As[cur][(wr + i * 16 + fr) * 32 + fk];
        #pragma unroll
        for (int j = 0; j < NJ; ++j) bfr[j] = *(bf16x8*)&Bs[cur][(wc + j * 16 + fr) * 32 + fk];
        #pragma unroll
        for (int i = 0; i < MI; ++i)
            #pragma unroll
            for (int j = 0; j < NJ; ++j)
                acc[i][j] = __builtin_amdgcn_mfma_f32_16x16x32_bf16(af[i], bfr[j], acc[i][j], 0, 0, 0);
        cur ^= 1;
    }

    const int rowbase = (lane >> 4) * 4;
    #pragma unroll
    for (int i = 0; i < MI; ++i) {
        #pragma unroll
        for (int j = 0; j < NJ; ++j) {
            const int n = bn + wc + j * 16 + fr;
            const float bn_v = bias ? bias[n] : 0.f;
            #pragma unroll
            for (int r = 0; r < 4; ++r) {
                const int m = bm + wr + i * 16 + rowbase + r;
                float v = acc[i][j][r] + bn_v;
                if (ACT) v = 0.5f * v * (1.0f + erff(v * 0.70710678118654752f));
                if (OUT_BF16) ((short*)Cout)[(size_t)m * N + n] = f2bf(v);
                else          ((float*)Cout)[(size_t)m * N + n] = v;
            }
        }
    }
}

// ---------------------------------------------------------------------------
// MERGED projection kernel: blocks 0..767 compute qkv (64x128 tile, bf16 out),
// blocks 768..1279 compute xq/xk split-bf16 (64x64 tile, hi/lo out).
// ---------------------------------------------------------------------------
__global__ __launch_bounds__(256) void proj_kernel(
    const short* __restrict__ xbf, const short* __restrict__ xlo,
    const short* __restrict__ inwbf, const float* __restrict__ in_b,
    const short* __restrict__ wqh, const short* __restrict__ wql,
    const short* __restrict__ wkh, const short* __restrict__ wkl,
    short* __restrict__ qkvbf,
    short* __restrict__ qh, short* __restrict__ ql,
    short* __restrict__ kh, short* __restrict__ kl)
{
    __shared__ short smem[12288];   // 24 KB arena
    const int bid  = blockIdx.x;
    const int tid  = threadIdx.x;
    const int wave = tid >> 6;
    const int lane = tid & 63;
    const int fr = lane & 15;
    const int fk = (lane >> 4) * 8;
    const int r0 = tid >> 2, ch = (tid & 3) * 8;

    if (bid < 768) {
        const int bm = (bid / 6) * 64;
        const int bn = (bid % 6) * 128;
        const int wr = (wave >> 1) * 32;
        const int wc = (wave & 1) * 64;
        short* As = smem;
        short* Bs = smem + 4096;

        f32x4 acc[2][4];
        #pragma unroll
        for (int i = 0; i < 2; ++i)
            #pragma unroll
            for (int j = 0; j < 4; ++j)
                acc[i][j] = (f32x4){0.f, 0.f, 0.f, 0.f};

        auto stage = [&](int buf, int k0) {
            __builtin_amdgcn_global_load_lds(
                (ga_int*)&xbf[(size_t)(bm + r0) * D_ + k0 + ch],
                (ls_int*)&As[buf * 2048 + tid * 8], 16, 0, 0);
            #pragma unroll
            for (int j = 0; j < 2; ++j)
                __builtin_amdgcn_global_load_lds(
                    (ga_int*)&inwbf[(size_t)(bn + r0 + j * 64) * D_ + k0 + ch],
                    (ls_int*)&Bs[buf * 4096 + (tid + j * 256) * 8], 16, 0, 0);
        };

        stage(0, 0);
        int cur = 0;
        for (int k0 = 0; k0 < D_; k0 += 32) {
            __syncthreads();
            if (k0 + 32 < D_) stage(cur ^ 1, k0 + 32);
            bf16x8 af[2], bfr[4];
            #pragma unroll
            for (int i = 0; i < 2; ++i) af[i]  = *(bf16x8*)&As[cur * 2048 + (wr + i * 16 + fr) * 32 + fk];
            #pragma unroll
            for (int j = 0; j < 4; ++j) bfr[j] = *(bf16x8*)&Bs[cur * 4096 + (wc + j * 16 + fr) * 32 + fk];
            #pragma unroll
            for (int i = 0; i < 2; ++i)
                #pragma unroll
                for (int j = 0; j < 4; ++j)
                    acc[i][j] = __builtin_amdgcn_mfma_f32_16x16x32_bf16(af[i], bfr[j], acc[i][j], 0, 0, 0);
            cur ^= 1;
        }

        const int rowbase = (lane >> 4) * 4;
        #pragma unroll
        for (int i = 0; i < 2; ++i)
            #pragma unroll
            for (int j = 0; j < 4; ++j) {
                const int n = bn + wc + j * 16 + fr;
                const float bv = in_b[n];
                #pragma unroll
                for (int r = 0; r < 4; ++r) {
                    const int m = bm + wr + i * 16 + rowbase + r;
                    qkvbf[(size_t)m * 768 + n] = f2bf(acc[i][j][r] + bv);
                }
            }
    } else {
        const int t = bid - 768;
        const int z = t >> 8;
        const int rem = t & 255;
        const int bm = (rem >> 1) * 64;
        const int bn = (rem & 1) * 64;
        const short* Wh = z ? wkh : wqh;
        const short* Wl = z ? wkl : wql;
        short* Oh = z ? kh : qh;
        short* Ol = z ? kl : ql;
        short* Ah = smem;
        short* Al = smem + 2048;
        short* Bh = smem + 4096;
        short* Bl = smem + 6144;

        const int wr = (wave >> 1) * 32;
        const int wc = (wave & 1) * 32;

        f32x4 acc[2][2];
        #pragma unroll
        for (int i = 0; i < 2; ++i)
            #pragma unroll
            for (int j = 0; j < 2; ++j)
                acc[i][j] = (f32x4){0.f, 0.f, 0.f, 0.f};

        for (int k0 = 0; k0 < D_; k0 += 32) {
            __builtin_amdgcn_global_load_lds((ga_int*)&xbf[(size_t)(bm + r0) * D_ + k0 + ch], (ls_int*)&Ah[tid * 8], 16, 0, 0);
            __builtin_amdgcn_global_load_lds((ga_int*)&xlo[(size_t)(bm + r0) * D_ + k0 + ch], (ls_int*)&Al[tid * 8], 16, 0, 0);
            __builtin_amdgcn_global_load_lds((ga_int*)&Wh[(size_t)(bn + r0) * D_ + k0 + ch], (ls_int*)&Bh[tid * 8], 16, 0, 0);
            __builtin_amdgcn_global_load_lds((ga_int*)&Wl[(size_t)(bn + r0) * D_ + k0 + ch], (ls_int*)&Bl[tid * 8], 16, 0, 0);
            __syncthreads();

            bf16x8 ah[2], al[2], bh[2], bl[2];
            #pragma unroll
            for (int i = 0; i < 2; ++i) {
                ah[i] = *(bf16x8*)&Ah[(wr + i * 16 + fr) * 32 + fk];
                al[i] = *(bf16x8*)&Al[(wr + i * 16 + fr) * 32 + fk];
            }
            #pragma unroll
            for (int j = 0; j < 2; ++j) {
                bh[j] = *(bf16x8*)&Bh[(wc + j * 16 + fr) * 32 + fk];
                bl[j] = *(bf16x8*)&Bl[(wc + j * 16 + fr) * 32 + fk];
            }
            #pragma unroll
            for (int i = 0; i < 2; ++i)
                #pragma unroll
                for (int j = 0; j < 2; ++j) {
                    acc[i][j] = __builtin_amdgcn_mfma_f32_16x16x32_bf16(ah[i], bh[j], acc[i][j], 0, 0, 0);
                    acc[i][j] = __builtin_amdgcn_mfma_f32_16x16x32_bf16(ah[i], bl[j], acc[i][j], 0, 0, 0);
                    acc[i][j] = __builtin_amdgcn_mfma_f32_16x16x32_bf16(al[i], bh[j], acc[i][j], 0, 0, 0);
                }
            __syncthreads();
        }

        const int rowbase = (lane >> 4) * 4;
        #pragma unroll
        for (int i = 0; i < 2; ++i)
            #pragma unroll
            for (int j = 0; j < 2; ++j) {
                const int n = bn + wc + j * 16 + fr;
                #pragma unroll
                for (int r = 0; r < 4; ++r) {
                    const int m = bm + wr + i * 16 + rowbase + r;
                    float v = acc[i][j][r];
                    short h = f2bf(v);
                    Oh[(size_t)m * RD_ + n] = h;
                    Ol[(size_t)m * RD_ + n] = f2bf(v - bf2f(h));
                }
            }
    }
}

// ---------------------------------------------------------------------------
// Split-bf16 MFMA logits: logits[b,q,c] = qh.kh + qh.kl + ql.kh (fp32 out).
// ---------------------------------------------------------------------------
__global__ __launch_bounds__(256) void logits_mfma(
    const short* __restrict__ qh, const short* __restrict__ ql,
    const short* __restrict__ kh, const short* __restrict__ kl,
    float* __restrict__ out)
{
    __shared__ short Ah[64 * 32], Al[64 * 32], Bh[64 * 32], Bl[64 * 32];
    const int tid  = threadIdx.x;
    const int wave = tid >> 6;
    const int lane = tid & 63;
    const int base = blockIdx.z * C_;
    const int bm = blockIdx.y * 64;
    const int bn = blockIdx.x * 64;
    const int wr = (wave >> 1) * 32;
    const int wc = (wave & 1) * 32;
    const int fr = lane & 15;
    const int fk = (lane >> 4) * 8;
    const int r0 = tid >> 2, ch = (tid & 3) * 8;

    f32x4 acc[2][2];
    #pragma unroll
    for (int i = 0; i < 2; ++i)
        #pragma unroll
        for (int j = 0; j < 2; ++j)
            acc[i][j] = (f32x4){0.f, 0.f, 0.f, 0.f};

    for (int k0 = 0; k0 < RD_; k0 += 32) {
        __builtin_amdgcn_global_load_lds((ga_int*)&qh[(size_t)(base + bm + r0) * RD_ + k0 + ch], (ls_int*)&Ah[tid * 8], 16, 0, 0);
        __builtin_amdgcn_global_load_lds((ga_int*)&ql[(size_t)(base + bm + r0) * RD_ + k0 + ch], (ls_int*)&Al[tid * 8], 16, 0, 0);
        __builtin_amdgcn_global_load_lds((ga_int*)&kh[(size_t)(base + bn + r0) * RD_ + k0 + ch], (ls_int*)&Bh[tid * 8], 16, 0, 0);
        __builtin_amdgcn_global_load_lds((ga_int*)&kl[(size_t)(base + bn + r0) * RD_ + k0 + ch], (ls_int*)&Bl[tid * 8], 16, 0, 0);
        __syncthreads();

        bf16x8 ah[2], al[2], bh[2], bl[2];
        #pragma unroll
        for (int i = 0; i < 2; ++i) {
            ah[i] = *(bf16x8*)&Ah[(wr + i * 16 + fr) * 32 + fk];
            al[i] = *(bf16x8*)&Al[(wr + i * 16 + fr) * 32 + fk];
        }
        #pragma unroll
        for (int j = 0; j < 2; ++j) {
            bh[j] = *(bf16x8*)&Bh[(wc + j * 16 + fr) * 32 + fk];
            bl[j] = *(bf16x8*)&Bl[(wc + j * 16 + fr) * 32 + fk];
        }
        #pragma unroll
        for (int i = 0; i < 2; ++i)
            #pragma unroll
            for (int j = 0; j < 2; ++j) {
                acc[i][j] = __builtin_amdgcn_mfma_f32_16x16x32_bf16(ah[i], bh[j], acc[i][j], 0, 0, 0);
                acc[i][j] = __builtin_amdgcn_mfma_f32_16x16x32_bf16(ah[i], bl[j], acc[i][j], 0, 0, 0);
                acc[i][j] = __builtin_amdgcn_mfma_f32_16x16x32_bf16(al[i], bh[j], acc[i][j], 0, 0, 0);
            }
        __syncthreads();
    }

    const int rowbase = (lane >> 4) * 4;
    #pragma unroll
    for (int i = 0; i < 2; ++i)
        #pragma unroll
        for (int j = 0; j < 2; ++j) {
            const int n = bn + wc + j * 16 + fr;
            #pragma unroll
            for (int r = 0; r < 4; ++r) {
                const int m = base + bm + wr + i * 16 + rowbase + r;
                out[(size_t)m * C_ + n] = acc[i][j][r];
            }
        }
}

// ---------------------------------------------------------------------------
// FUSED top-16 + attention, ONE WAVE per (b,q) row, 2048 blocks.
// XCD batch-affinity remap (bijective, perf heuristic only).
// ---------------------------------------------------------------------------
__global__ __launch_bounds__(256) void topk_attn_kernel(
    const float* __restrict__ logits, const short* __restrict__ qkv,
    short* __restrict__ ctxbf)
{
    const int jb   = blockIdx.x;
    const int xcd  = jb & 7;
    const int slot = jb >> 3;                       // 0..255
    const int batch = xcd * 2 + (slot >> 7);        // 2 batches per XCD
    const int rb    = (batch << 7) + (slot & 127);  // row-block 0..2047

    const int wave = threadIdx.x >> 6;
    const int lane = threadIdx.x & 63;
    const int row  = rb * 4 + wave;
    const int bbase = row & ~(C_ - 1);

    // ---- top-16 ----
    const float* lrow = logits + (size_t)row * C_;
    float v[8];
    #pragma unroll
    for (int j = 0; j < 8; ++j) v[j] = lrow[lane * 8 + j];

    int ii[K_];
    #pragma unroll
    for (int sel = 0; sel < K_; ++sel) {
        float bv = v[0]; int bj = 0;
        #pragma unroll
        for (int j = 1; j < 8; ++j)
            if (v[j] > bv) { bv = v[j]; bj = j; }     // strict > : lowest j on ties
        float wb = bv;
        #pragma unroll
        for (int s = 1; s < 64; s <<= 1)
            wb = fmaxf(wb, __shfl_xor(wb, s, 64));
        unsigned long long mask = __ballot(bv == wb);
        int wl = __ffsll(mask) - 1;                    // lowest lane = lowest index
        int wj = __shfl(bj, wl, 64);
        ii[sel] = wl * 8 + wj;
        #pragma unroll
        for (int j = 0; j < 8; ++j)
            if (lane == wl && bj == j) v[j] = -INFINITY;
    }

    // ---- attention over the 16 selected slots (bf16 loads, fp32 math) ----
    const short* qrow = qkv + (size_t)row * 768;
    float4 qv = ld4bf(qrow + lane * 4);

    float s[K_];
    #pragma unroll
    for (int k = 0; k < K_; ++k) {
        float4 kv = ld4bf(qkv + (size_t)(bbase + ii[k]) * 768 + 256 + lane * 4);
        float p = qv.x * kv.x + qv.y * kv.y + qv.z * kv.z + qv.w * kv.w;
        p += __shfl_xor(p, 1, 64);
        p += __shfl_xor(p, 2, 64);
        p += __shfl_xor(p, 4, 64);
        s[k] = p * 0.17677669529663687f;
    }

    float m = s[0];
    #pragma unroll
    for (int k = 1; k < K_; ++k) m = fmaxf(m, s[k]);
    float ssum = 0.f;
    #pragma unroll
    for (int k = 0; k < K_; ++k) { s[k] = __expf(s[k] - m); ssum += s[k]; }
    const float inv = 1.f / ssum;

    float4 acc = {0.f, 0.f, 0.f, 0.f};
    #pragma unroll
    for (int k = 0; k < K_; ++k) {
        float4 vvv = ld4bf(qkv + (size_t)(bbase + ii[k]) * 768 + 512 + lane * 4);
        float w = s[k] * inv;
        acc.x += w * vvv.x; acc.y += w * vvv.y; acc.z += w * vvv.z; acc.w += w * vvv.w;
    }

    unsigned lo = (unsigned)(unsigned short)f2bf(acc.x) | ((unsigned)(unsigned short)f2bf(acc.y) << 16);
    unsigned hi = (unsigned)(unsigned short)f2bf(acc.z) | ((unsigned)(unsigned short)f2bf(acc.w) << 16);
    uint2 pk = {lo, hi};
    *(uint2*)(ctxbf + (size_t)row * D_ + lane * 4) = pk;
}

// ---------------------------------------------------------------------------
// FUSED GEMM + bias + bf16-residual + LayerNorm. 512 threads, BM=32, BN=256,
// grid M/32 = 256. 8 waves: waves 0-3 -> rows 0-15, waves 4-7 -> rows 16-31,
// all sharing one Bs stage -> W traffic halved vs BM=16 (the kernel is
// staging-BW-bound: ~585cy staging vs ~40cy MFMA per K-step at BM=16).
// Same waves/CU as before (1x8 vs 2x4); BW-bound so barrier coupling is ok.
// ---------------------------------------------------------------------------
template<int KD, int WF32, int WBF>
__global__ __launch_bounds__(512) void gemm_ln_mfma(
    const short* __restrict__ A, const short* __restrict__ W,
    const float* __restrict__ bias, const short* __restrict__ resbf,
    const float* __restrict__ g, const float* __restrict__ beta,
    float* __restrict__ outf, short* __restrict__ outbf)
{
    __shared__ short As[2][32 * 32];
    __shared__ short Bs[2][256 * 32];
    __shared__ float part[8][16][2];

    const int tid  = threadIdx.x;        // 0..511
    const int wave = tid >> 6;           // 0..7
    const int lane = tid & 63;
    const int bm = blockIdx.x * 32;
    const int half = wave >> 2;          // 0: rows 0-15, 1: rows 16-31
    const int wc = (wave & 3) * 64;
    const int fr = lane & 15;
    const int fk = (lane >> 4) * 8;
    const int r0 = tid >> 2, ch = (tid & 3) * 8;

    f32x4 acc[4];
    #pragma unroll
    for (int j = 0; j < 4; ++j) acc[j] = (f32x4){0.f, 0.f, 0.f, 0.f};

    auto stage = [&](int buf, int k0) {
        if (tid < 128)
            __builtin_amdgcn_global_load_lds(
                (ga_int*)&A[(size_t)(bm + r0) * KD + k0 + ch],
                (ls_int*)&As[buf][tid * 8], 16, 0, 0);
        #pragma unroll
        for (int j = 0; j < 2; ++j)
            __builtin_amdgcn_global_load_lds(
                (ga_int*)&W[(size_t)(r0 + j * 128) * KD + k0 + ch],
                (ls_int*)&Bs[buf][(tid + j * 512) * 8], 16, 0, 0);
    };

    stage(0, 0);
    int cur = 0;

    for (int k0 = 0; k0 < KD; k0 += 32) {
        __syncthreads();
        if (k0 + 32 < KD) stage(cur ^ 1, k0 + 32);

        bf16x8 af = *(bf16x8*)&As[cur][(half * 16 + fr) * 32 + fk];
        bf16x8 bfr[4];
        #pragma unroll
        for (int j = 0; j < 4; ++j) bfr[j] = *(bf16x8*)&Bs[cur][(wc + j * 16 + fr) * 32 + fk];
        #pragma unroll
        for (int j = 0; j < 4; ++j)
            acc[j] = __builtin_amdgcn_mfma_f32_16x16x32_bf16(af, bfr[j], acc[j], 0, 0, 0);
        cur ^= 1;
    }

    const int rowbase = (lane >> 4) * 4;
    float vv[4][4];
    float sum[4] = {0.f, 0.f, 0.f, 0.f};
    float sq[4]  = {0.f, 0.f, 0.f, 0.f};

    #pragma unroll
    for (int j = 0; j < 4; ++j) {
        const int n = wc + j * 16 + fr;
        const float bv = bias[n];
        #pragma unroll
        for (int r = 0; r < 4; ++r) {
            const int m = bm + half * 16 + rowbase + r;
            float v = acc[j][r] + bv + bf2f(resbf[(size_t)m * D_ + n]);
            vv[j][r] = v;
            sum[r] += v;
            sq[r]  += v * v;
        }
    }

    #pragma unroll
    for (int r = 0; r < 4; ++r)
        #pragma unroll
        for (int s = 1; s < 16; s <<= 1) {
            sum[r] += __shfl_xor(sum[r], s, 64);
            sq[r]  += __shfl_xor(sq[r],  s, 64);
        }

    if (fr == 0) {
        #pragma unroll
        for (int r = 0; r < 4; ++r) {
            part[wave][rowbase + r][0] = sum[r];
            part[wave][rowbase + r][1] = sq[r];
        }
    }
    __syncthreads();

    #pragma unroll
    for (int r = 0; r < 4; ++r) {
        const int ml = rowbase + r;
        const int w0 = half * 4;
        const float S = part[w0][ml][0] + part[w0 + 1][ml][0] + part[w0 + 2][ml][0] + part[w0 + 3][ml][0];
        const float Q = part[w0][ml][1] + part[w0 + 1][ml][1] + part[w0 + 2][ml][1] + part[w0 + 3][ml][1];
        const float mean = S * (1.0f / D_);
        const float var  = Q * (1.0f / D_) - mean * mean;
        const float rstd = rsqrtf(var + 1e-5f);
        const int m = bm + half * 16 + ml;
        #pragma unroll
        for (int j = 0; j < 4; ++j) {
            const int n = wc + j * 16 + fr;
            float o = (vv[j][r] - mean) * rstd * g[n] + beta[n];
            if (WF32) outf[(size_t)m * D_ + n] = o;
            if (WBF)  outbf[(size_t)m * D_ + n] = f2bf(o);
        }
    }
}

// ---------------------------------------------------------------------------
extern "C" void kernel_launch(void* const* d_in, const int* in_sizes, int n_in,
                              void* d_out, int out_size, void* d_ws, size_t ws_size,
                              hipStream_t stream)
{
    const float* x      = (const float*)d_in[0];
    const float* wq_rec = (const float*)d_in[1];
    const float* wk_rec = (const float*)d_in[2];
    const float* in_w   = (const float*)d_in[3];
    const float* in_b   = (const float*)d_in[4];
    const float* out_w  = (const float*)d_in[5];
    const float* out_b  = (const float*)d_in[6];
    const float* ln1_g  = (const float*)d_in[7];
    const float* ln1_b  = (const float*)d_in[8];
    const float* w1     = (const float*)d_in[9];
    const float* b1     = (const float*)d_in[10];
    const float* w2     = (const float*)d_in[11];
    const float* b2     = (const float*)d_in[12];
    const float* ln2_g  = (const float*)d_in[13];
    const float* ln2_b  = (const float*)d_in[14];
    float* out = (float*)d_out;

    // ---- workspace layout ----
    short* qkvbf = (short*)d_ws;                    // M*768 sh (bf16 q|k|v)
    short* qh    = qkvbf + (size_t)M_ * 768;        // M*128 sh
    short* ql    = qh + (size_t)M_ * RD_;
    short* kh    = ql + (size_t)M_ * RD_;
    short* kl    = kh + (size_t)M_ * RD_;
    float* U     = (float*)(kl + (size_t)M_ * RD_);
    float* logits = U;                                  // M*512 f
    short* ctxbf  = (short*)(U + (size_t)M_ * 512);     // M*256 sh
    short* x1bf   = ctxbf + (size_t)M_ * D_;            // M*256 sh
    short* hbf    = x1bf  + (size_t)M_ * D_;            // M*1024 sh
    short* xbf    = hbf   + (size_t)M_ * FFN_;          // M*256 sh
    short* xlo    = xbf   + (size_t)M_ * D_;
    short* inwbf  = xlo   + (size_t)M_ * D_;
    short* outwbf = inwbf + (size_t)768 * D_;
    short* w1bf   = outwbf + (size_t)D_ * D_;
    short* w2bf   = w1bf  + (size_t)FFN_ * D_;
    short* wqh    = w2bf  + (size_t)D_ * FFN_;
    short* wql    = wqh + (size_t)RD_ * D_;
    short* wkh    = wql + (size_t)RD_ * D_;
    short* wkl    = wkh + (size_t)RD_ * D_;

    dim3 blk(256);

    // 0) all bf16 conversions (+ hi/lo splits), one launch
    convert_all_kernel<<<dim3((N8_ALL + 255) / 256), blk, 0, stream>>>(
        x, in_w, out_w, w1, w2, wq_rec, wk_rec,
        xbf, xlo, inwbf, outwbf, w1bf, w2bf, wqh, wql, wkh, wkl);

    // 1) merged qkv + xq/xk projections (1280 blocks)
    proj_kernel<<<dim3(1280), blk, 0, stream>>>(
        xbf, xlo, inwbf, in_b, wqh, wql, wkh, wkl, qkvbf, qh, ql, kh, kl);
    // 2) logits, split-bf16 MFMA (1024 blocks)
    logits_mfma<<<dim3(C_ / 64, C_ / 64, B_), blk, 0, stream>>>(qh, ql, kh, kl, logits);
    // 3) fused top-16 + gathered attention -> ctx (bf16)
    topk_attn_kernel<<<dim3(M_ / 4), blk, 0, stream>>>(logits, qkvbf, ctxbf);
    // 4) out projection + bf16-residual(x) + LN1 -> x1bf (256 blocks, 512 thr)
    gemm_ln_mfma<256, 0, 1><<<dim3(M_ / 32), dim3(512), 0, stream>>>(
        ctxbf, outwbf, out_b, xbf, ln1_g, ln1_b, nullptr, x1bf);
    // 5) h = gelu(x1 @ w1^T + b1) (MFMA, 64x128 -> 1024 blocks, bf16 out)
    gemm_mfma<64, 128, 1, 1><<<dim3(FFN_ / 128, M_ / 64), blk, 0, stream>>>(x1bf, w1bf, b1, hbf, M_, FFN_, D_);
    // 6) y = h @ w2^T + b2 + bf16-residual(x1) + LN2 -> out (256 blocks, 512 thr)
    gemm_ln_mfma<1024, 1, 0><<<dim3(M_ / 32), dim3(512), 0, stream>>>(
        hbf, w2bf, b2, x1bf, ln2_g, ln2_b, out, nullptr);
}

// Round 17
// 104.657 us; speedup vs baseline: 1.0112x; 1.0112x over previous
//
#include <hip/hip_runtime.h>
#include <hip/hip_bf16.h>
#include <math.h>

#define B_   16
#define C_   512
#define D_   256
#define K_   16
#define RD_  128
#define H_   8
#define HD_  32
#define FFN_ 1024
#define M_   (B_ * C_)   // 8192 rows

typedef __attribute__((ext_vector_type(8))) short bf16x8;
typedef __attribute__((ext_vector_type(4))) float f32x4;

typedef __attribute__((address_space(1))) const int ga_int;
typedef __attribute__((address_space(3))) int ls_int;

static __device__ __forceinline__ short f2bf(float v) {
    __hip_bfloat16 h = __float2bfloat16(v);
    return *(short*)&h;
}
static __device__ __forceinline__ float bf2f(short s) {
    __hip_bfloat16 h = *(__hip_bfloat16*)&s;
    return __bfloat162float(h);
}
static __device__ __forceinline__ float4 ld4bf(const short* p) {
    uint2 u = *(const uint2*)p;
    float4 r;
    r.x = __uint_as_float((u.x & 0xffffu) << 16);
    r.y = __uint_as_float(u.x & 0xffff0000u);
    r.z = __uint_as_float((u.y & 0xffffu) << 16);
    r.w = __uint_as_float(u.y & 0xffff0000u);
    return r;
}

// ---------------------------------------------------------------------------
// All fp32->bf16 conversions in ONE kernel. x emits HI+LO; wq/wk emit HI+LO.
// ---------------------------------------------------------------------------
#define N8_X    (M_ * D_ / 8)
#define N8_INW  (768 * D_ / 8)
#define N8_OUTW (D_ * D_ / 8)
#define N8_W1   (FFN_ * D_ / 8)
#define N8_W2   (D_ * FFN_ / 8)
#define N8_WQ   (RD_ * D_ / 8)
#define N8_ALL  (N8_X + N8_INW + N8_OUTW + N8_W1 + N8_W2 + 2 * N8_WQ)

__global__ __launch_bounds__(256) void convert_all_kernel(
    const float* __restrict__ x, const float* __restrict__ inw,
    const float* __restrict__ outw, const float* __restrict__ w1,
    const float* __restrict__ w2, const float* __restrict__ wq,
    const float* __restrict__ wk,
    short* __restrict__ xbf, short* __restrict__ xlo,
    short* __restrict__ inwbf, short* __restrict__ outwbf,
    short* __restrict__ w1bf, short* __restrict__ w2bf,
    short* __restrict__ wqh, short* __restrict__ wql,
    short* __restrict__ wkh, short* __restrict__ wkl)
{
    int i = blockIdx.x * 256 + threadIdx.x;
    if (i >= N8_ALL) return;

    const float* s; short* dh; short* dl = nullptr; int off;
    if      (i < N8_X)                    { s = x;    dh = xbf;    dl = xlo; off = i; }
    else if (i < N8_X + N8_INW)           { s = inw;  dh = inwbf;  off = i - N8_X; }
    else if (i < N8_X + N8_INW + N8_OUTW) { s = outw; dh = outwbf; off = i - N8_X - N8_INW; }
    else if (i < N8_X + N8_INW + N8_OUTW + N8_W1)
                                          { s = w1;   dh = w1bf;   off = i - N8_X - N8_INW - N8_OUTW; }
    else if (i < N8_X + N8_INW + N8_OUTW + N8_W1 + N8_W2)
                                          { s = w2;   dh = w2bf;   off = i - N8_X - N8_INW - N8_OUTW - N8_W1; }
    else if (i < N8_X + N8_INW + N8_OUTW + N8_W1 + N8_W2 + N8_WQ)
                                          { s = wq;   dh = wqh; dl = wql; off = i - N8_X - N8_INW - N8_OUTW - N8_W1 - N8_W2; }
    else                                  { s = wk;   dh = wkh; dl = wkl; off = i - N8_X - N8_INW - N8_OUTW - N8_W1 - N8_W2 - N8_WQ; }

    const float4* sp = (const float4*)s + (size_t)off * 2;
    float4 v0 = sp[0], v1 = sp[1];
    float f[8] = {v0.x, v0.y, v0.z, v0.w, v1.x, v1.y, v1.z, v1.w};
    short rh[8], rl[8];
    #pragma unroll
    for (int j = 0; j < 8; ++j) {
        rh[j] = f2bf(f[j]);
        rl[j] = f2bf(f[j] - bf2f(rh[j]));
    }
    *(bf16x8*)(dh + (size_t)off * 8) = *(bf16x8*)rh;
    if (dl) *(bf16x8*)(dl + (size_t)off * 8) = *(bf16x8*)rl;
}

// ---------------------------------------------------------------------------
// bf16 MFMA GEMM (standalone; used for MLP1). Double-buffered gload_lds.
// ---------------------------------------------------------------------------
template<int BM, int BN, int OUT_BF16, int ACT>
__global__ __launch_bounds__(256) void gemm_mfma(
    const short* __restrict__ A, const short* __restrict__ W,
    const float* __restrict__ bias, void* __restrict__ Cout,
    int M, int N, int Kd)
{
    __shared__ short As[2][BM * 32];
    __shared__ short Bs[2][BN * 32];
    const int tid  = threadIdx.x;
    const int wave = tid >> 6;
    const int lane = tid & 63;
    const int bm = blockIdx.y * BM;
    const int bn = blockIdx.x * BN;
    constexpr int MI = BM / 32;
    constexpr int NJ = BN / 32;
    const int wr = (wave >> 1) * (BM / 2);
    const int wc = (wave & 1) * (BN / 2);

    const int fr = lane & 15;
    const int fk = (lane >> 4) * 8;
    const int r0 = tid >> 2, ch = (tid & 3) * 8;

    f32x4 acc[MI][NJ];
    #pragma unroll
    for (int i = 0; i < MI; ++i)
        #pragma unroll
        for (int j = 0; j < NJ; ++j)
            acc[i][j] = (f32x4){0.f, 0.f, 0.f, 0.f};

    auto stage = [&](int buf, int k0) {
        #pragma unroll
        for (int i = 0; i < BM / 64; ++i)
            __builtin_amdgcn_global_load_lds(
                (ga_int*)&A[(size_t)(bm + r0 + i * 64) * Kd + k0 + ch],
                (ls_int*)&As[buf][(tid + i * 256) * 8], 16, 0, 0);
        #pragma unroll
        for (int j = 0; j < BN / 64; ++j)
            __builtin_amdgcn_global_load_lds(
                (ga_int*)&W[(size_t)(bn + r0 + j * 64) * Kd + k0 + ch],
                (ls_int*)&Bs[buf][(tid + j * 256) * 8], 16, 0, 0);
    };

    stage(0, 0);
    int cur = 0;

    for (int k0 = 0; k0 < Kd; k0 += 32) {
        __syncthreads();
        if (k0 + 32 < Kd) stage(cur ^ 1, k0 + 32);

        bf16x8 af[MI], bfr[NJ];
        #pragma unroll
        for (int i = 0; i < MI; ++i) af[i]  = *(bf16x8*)&As[cur][(wr + i * 16 + fr) * 32 + fk];
        #pragma unroll
        for (int j = 0; j < NJ; ++j) bfr[j] = *(bf16x8*)&Bs[cur][(wc + j * 16 + fr) * 32 + fk];
        #pragma unroll
        for (int i = 0; i < MI; ++i)
            #pragma unroll
            for (int j = 0; j < NJ; ++j)
                acc[i][j] = __builtin_amdgcn_mfma_f32_16x16x32_bf16(af[i], bfr[j], acc[i][j], 0, 0, 0);
        cur ^= 1;
    }

    const int rowbase = (lane >> 4) * 4;
    #pragma unroll
    for (int i = 0; i < MI; ++i) {
        #pragma unroll
        for (int j = 0; j < NJ; ++j) {
            const int n = bn + wc + j * 16 + fr;
            const float bn_v = bias ? bias[n] : 0.f;
            #pragma unroll
            for (int r = 0; r < 4; ++r) {
                const int m = bm + wr + i * 16 + rowbase + r;
                float v = acc[i][j][r] + bn_v;
                if (ACT) v = 0.5f * v * (1.0f + erff(v * 0.70710678118654752f));
                if (OUT_BF16) ((short*)Cout)[(size_t)m * N + n] = f2bf(v);
                else          ((float*)Cout)[(size_t)m * N + n] = v;
            }
        }
    }
}

// ---------------------------------------------------------------------------
// MERGED projection kernel: blocks 0..767 compute qkv (64x128 tile, bf16 out),
// blocks 768..1279 compute xq/xk split-bf16 (64x64 tile, hi/lo out).
// ---------------------------------------------------------------------------
__global__ __launch_bounds__(256) void proj_kernel(
    const short* __restrict__ xbf, const short* __restrict__ xlo,
    const short* __restrict__ inwbf, const float* __restrict__ in_b,
    const short* __restrict__ wqh, const short* __restrict__ wql,
    const short* __restrict__ wkh, const short* __restrict__ wkl,
    short* __restrict__ qkvbf,
    short* __restrict__ qh, short* __restrict__ ql,
    short* __restrict__ kh, short* __restrict__ kl)
{
    __shared__ short smem[12288];   // 24 KB arena
    const int bid  = blockIdx.x;
    const int tid  = threadIdx.x;
    const int wave = tid >> 6;
    const int lane = tid & 63;
    const int fr = lane & 15;
    const int fk = (lane >> 4) * 8;
    const int r0 = tid >> 2, ch = (tid & 3) * 8;

    if (bid < 768) {
        const int bm = (bid / 6) * 64;
        const int bn = (bid % 6) * 128;
        const int wr = (wave >> 1) * 32;
        const int wc = (wave & 1) * 64;
        short* As = smem;
        short* Bs = smem + 4096;

        f32x4 acc[2][4];
        #pragma unroll
        for (int i = 0; i < 2; ++i)
            #pragma unroll
            for (int j = 0; j < 4; ++j)
                acc[i][j] = (f32x4){0.f, 0.f, 0.f, 0.f};

        auto stage = [&](int buf, int k0) {
            __builtin_amdgcn_global_load_lds(
                (ga_int*)&xbf[(size_t)(bm + r0) * D_ + k0 + ch],
                (ls_int*)&As[buf * 2048 + tid * 8], 16, 0, 0);
            #pragma unroll
            for (int j = 0; j < 2; ++j)
                __builtin_amdgcn_global_load_lds(
                    (ga_int*)&inwbf[(size_t)(bn + r0 + j * 64) * D_ + k0 + ch],
                    (ls_int*)&Bs[buf * 4096 + (tid + j * 256) * 8], 16, 0, 0);
        };

        stage(0, 0);
        int cur = 0;
        for (int k0 = 0; k0 < D_; k0 += 32) {
            __syncthreads();
            if (k0 + 32 < D_) stage(cur ^ 1, k0 + 32);
            bf16x8 af[2], bfr[4];
            #pragma unroll
            for (int i = 0; i < 2; ++i) af[i]  = *(bf16x8*)&As[cur * 2048 + (wr + i * 16 + fr) * 32 + fk];
            #pragma unroll
            for (int j = 0; j < 4; ++j) bfr[j] = *(bf16x8*)&Bs[cur * 4096 + (wc + j * 16 + fr) * 32 + fk];
            #pragma unroll
            for (int i = 0; i < 2; ++i)
                #pragma unroll
                for (int j = 0; j < 4; ++j)
                    acc[i][j] = __builtin_amdgcn_mfma_f32_16x16x32_bf16(af[i], bfr[j], acc[i][j], 0, 0, 0);
            cur ^= 1;
        }

        const int rowbase = (lane >> 4) * 4;
        #pragma unroll
        for (int i = 0; i < 2; ++i)
            #pragma unroll
            for (int j = 0; j < 4; ++j) {
                const int n = bn + wc + j * 16 + fr;
                const float bv = in_b[n];
                #pragma unroll
                for (int r = 0; r < 4; ++r) {
                    const int m = bm + wr + i * 16 + rowbase + r;
                    qkvbf[(size_t)m * 768 + n] = f2bf(acc[i][j][r] + bv);
                }
            }
    } else {
        const int t = bid - 768;
        const int z = t >> 8;
        const int rem = t & 255;
        const int bm = (rem >> 1) * 64;
        const int bn = (rem & 1) * 64;
        const short* Wh = z ? wkh : wqh;
        const short* Wl = z ? wkl : wql;
        short* Oh = z ? kh : qh;
        short* Ol = z ? kl : ql;
        short* Ah = smem;
        short* Al = smem + 2048;
        short* Bh = smem + 4096;
        short* Bl = smem + 6144;

        const int wr = (wave >> 1) * 32;
        const int wc = (wave & 1) * 32;

        f32x4 acc[2][2];
        #pragma unroll
        for (int i = 0; i < 2; ++i)
            #pragma unroll
            for (int j = 0; j < 2; ++j)
                acc[i][j] = (f32x4){0.f, 0.f, 0.f, 0.f};

        for (int k0 = 0; k0 < D_; k0 += 32) {
            __builtin_amdgcn_global_load_lds((ga_int*)&xbf[(size_t)(bm + r0) * D_ + k0 + ch], (ls_int*)&Ah[tid * 8], 16, 0, 0);
            __builtin_amdgcn_global_load_lds((ga_int*)&xlo[(size_t)(bm + r0) * D_ + k0 + ch], (ls_int*)&Al[tid * 8], 16, 0, 0);
            __builtin_amdgcn_global_load_lds((ga_int*)&Wh[(size_t)(bn + r0) * D_ + k0 + ch], (ls_int*)&Bh[tid * 8], 16, 0, 0);
            __builtin_amdgcn_global_load_lds((ga_int*)&Wl[(size_t)(bn + r0) * D_ + k0 + ch], (ls_int*)&Bl[tid * 8], 16, 0, 0);
            __syncthreads();

            bf16x8 ah[2], al[2], bh[2], bl[2];
            #pragma unroll
            for (int i = 0; i < 2; ++i) {
                ah[i] = *(bf16x8*)&Ah[(wr + i * 16 + fr) * 32 + fk];
                al[i] = *(bf16x8*)&Al[(wr + i * 16 + fr) * 32 + fk];
            }
            #pragma unroll
            for (int j = 0; j < 2; ++j) {
                bh[j] = *(bf16x8*)&Bh[(wc + j * 16 + fr) * 32 + fk];
                bl[j] = *(bf16x8*)&Bl[(wc + j * 16 + fr) * 32 + fk];
            }
            #pragma unroll
            for (int i = 0; i < 2; ++i)
                #pragma unroll
                for (int j = 0; j < 2; ++j) {
                    acc[i][j] = __builtin_amdgcn_mfma_f32_16x16x32_bf16(ah[i], bh[j], acc[i][j], 0, 0, 0);
                    acc[i][j] = __builtin_amdgcn_mfma_f32_16x16x32_bf16(ah[i], bl[j], acc[i][j], 0, 0, 0);
                    acc[i][j] = __builtin_amdgcn_mfma_f32_16x16x32_bf16(al[i], bh[j], acc[i][j], 0, 0, 0);
                }
            __syncthreads();
        }

        const int rowbase = (lane >> 4) * 4;
        #pragma unroll
        for (int i = 0; i < 2; ++i)
            #pragma unroll
            for (int j = 0; j < 2; ++j) {
                const int n = bn + wc + j * 16 + fr;
                #pragma unroll
                for (int r = 0; r < 4; ++r) {
                    const int m = bm + wr + i * 16 + rowbase + r;
                    float v = acc[i][j][r];
                    short h = f2bf(v);
                    Oh[(size_t)m * RD_ + n] = h;
                    Ol[(size_t)m * RD_ + n] = f2bf(v - bf2f(h));
                }
            }
    }
}

// ---------------------------------------------------------------------------
// Split-bf16 MFMA logits: logits[b,q,c] = qh.kh + qh.kl + ql.kh (fp32 out).
// ---------------------------------------------------------------------------
__global__ __launch_bounds__(256) void logits_mfma(
    const short* __restrict__ qh, const short* __restrict__ ql,
    const short* __restrict__ kh, const short* __restrict__ kl,
    float* __restrict__ out)
{
    __shared__ short Ah[64 * 32], Al[64 * 32], Bh[64 * 32], Bl[64 * 32];
    const int tid  = threadIdx.x;
    const int wave = tid >> 6;
    const int lane = tid & 63;
    const int base = blockIdx.z * C_;
    const int bm = blockIdx.y * 64;
    const int bn = blockIdx.x * 64;
    const int wr = (wave >> 1) * 32;
    const int wc = (wave & 1) * 32;
    const int fr = lane & 15;
    const int fk = (lane >> 4) * 8;
    const int r0 = tid >> 2, ch = (tid & 3) * 8;

    f32x4 acc[2][2];
    #pragma unroll
    for (int i = 0; i < 2; ++i)
        #pragma unroll
        for (int j = 0; j < 2; ++j)
            acc[i][j] = (f32x4){0.f, 0.f, 0.f, 0.f};

    for (int k0 = 0; k0 < RD_; k0 += 32) {
        __builtin_amdgcn_global_load_lds((ga_int*)&qh[(size_t)(base + bm + r0) * RD_ + k0 + ch], (ls_int*)&Ah[tid * 8], 16, 0, 0);
        __builtin_amdgcn_global_load_lds((ga_int*)&ql[(size_t)(base + bm + r0) * RD_ + k0 + ch], (ls_int*)&Al[tid * 8], 16, 0, 0);
        __builtin_amdgcn_global_load_lds((ga_int*)&kh[(size_t)(base + bn + r0) * RD_ + k0 + ch], (ls_int*)&Bh[tid * 8], 16, 0, 0);
        __builtin_amdgcn_global_load_lds((ga_int*)&kl[(size_t)(base + bn + r0) * RD_ + k0 + ch], (ls_int*)&Bl[tid * 8], 16, 0, 0);
        __syncthreads();

        bf16x8 ah[2], al[2], bh[2], bl[2];
        #pragma unroll
        for (int i = 0; i < 2; ++i) {
            ah[i] = *(bf16x8*)&Ah[(wr + i * 16 + fr) * 32 + fk];
            al[i] = *(bf16x8*)&Al[(wr + i * 16 + fr) * 32 + fk];
        }
        #pragma unroll
        for (int j = 0; j < 2; ++j) {
            bh[j] = *(bf16x8*)&Bh[(wc + j * 16 + fr) * 32 + fk];
            bl[j] = *(bf16x8*)&Bl[(wc + j * 16 + fr) * 32 + fk];
        }
        #pragma unroll
        for (int i = 0; i < 2; ++i)
            #pragma unroll
            for (int j = 0; j < 2; ++j) {
                acc[i][j] = __builtin_amdgcn_mfma_f32_16x16x32_bf16(ah[i], bh[j], acc[i][j], 0, 0, 0);
                acc[i][j] = __builtin_amdgcn_mfma_f32_16x16x32_bf16(ah[i], bl[j], acc[i][j], 0, 0, 0);
                acc[i][j] = __builtin_amdgcn_mfma_f32_16x16x32_bf16(al[i], bh[j], acc[i][j], 0, 0, 0);
            }
        __syncthreads();
    }

    const int rowbase = (lane >> 4) * 4;
    #pragma unroll
    for (int i = 0; i < 2; ++i)
        #pragma unroll
        for (int j = 0; j < 2; ++j) {
            const int n = bn + wc + j * 16 + fr;
            #pragma unroll
            for (int r = 0; r < 4; ++r) {
                const int m = base + bm + wr + i * 16 + rowbase + r;
                out[(size_t)m * C_ + n] = acc[i][j][r];
            }
        }
}

// ---------------------------------------------------------------------------
// FUSED top-16 + attention, ONE WAVE per (b,q) row, 2048 blocks.
// XCD batch-affinity remap (bijective, perf heuristic only).
// ---------------------------------------------------------------------------
__global__ __launch_bounds__(256) void topk_attn_kernel(
    const float* __restrict__ logits, const short* __restrict__ qkv,
    short* __restrict__ ctxbf)
{
    const int jb   = blockIdx.x;
    const int xcd  = jb & 7;
    const int slot = jb >> 3;                       // 0..255
    const int batch = xcd * 2 + (slot >> 7);        // 2 batches per XCD
    const int rb    = (batch << 7) + (slot & 127);  // row-block 0..2047

    const int wave = threadIdx.x >> 6;
    const int lane = threadIdx.x & 63;
    const int row  = rb * 4 + wave;
    const int bbase = row & ~(C_ - 1);

    // ---- top-16 ----
    const float* lrow = logits + (size_t)row * C_;
    float v[8];
    #pragma unroll
    for (int j = 0; j < 8; ++j) v[j] = lrow[lane * 8 + j];

    int ii[K_];
    #pragma unroll
    for (int sel = 0; sel < K_; ++sel) {
        float bv = v[0]; int bj = 0;
        #pragma unroll
        for (int j = 1; j < 8; ++j)
            if (v[j] > bv) { bv = v[j]; bj = j; }     // strict > : lowest j on ties
        float wb = bv;
        #pragma unroll
        for (int s = 1; s < 64; s <<= 1)
            wb = fmaxf(wb, __shfl_xor(wb, s, 64));
        unsigned long long mask = __ballot(bv == wb);
        int wl = __ffsll(mask) - 1;                    // lowest lane = lowest index
        int wj = __shfl(bj, wl, 64);
        ii[sel] = wl * 8 + wj;
        #pragma unroll
        for (int j = 0; j < 8; ++j)
            if (lane == wl && bj == j) v[j] = -INFINITY;
    }

    // ---- attention over the 16 selected slots (bf16 loads, fp32 math) ----
    const short* qrow = qkv + (size_t)row * 768;
    float4 qv = ld4bf(qrow + lane * 4);

    float s[K_];
    #pragma unroll
    for (int k = 0; k < K_; ++k) {
        float4 kv = ld4bf(qkv + (size_t)(bbase + ii[k]) * 768 + 256 + lane * 4);
        float p = qv.x * kv.x + qv.y * kv.y + qv.z * kv.z + qv.w * kv.w;
        p += __shfl_xor(p, 1, 64);
        p += __shfl_xor(p, 2, 64);
        p += __shfl_xor(p, 4, 64);
        s[k] = p * 0.17677669529663687f;
    }

    float m = s[0];
    #pragma unroll
    for (int k = 1; k < K_; ++k) m = fmaxf(m, s[k]);
    float ssum = 0.f;
    #pragma unroll
    for (int k = 0; k < K_; ++k) { s[k] = __expf(s[k] - m); ssum += s[k]; }
    const float inv = 1.f / ssum;

    float4 acc = {0.f, 0.f, 0.f, 0.f};
    #pragma unroll
    for (int k = 0; k < K_; ++k) {
        float4 vvv = ld4bf(qkv + (size_t)(bbase + ii[k]) * 768 + 512 + lane * 4);
        float w = s[k] * inv;
        acc.x += w * vvv.x; acc.y += w * vvv.y; acc.z += w * vvv.z; acc.w += w * vvv.w;
    }

    unsigned lo = (unsigned)(unsigned short)f2bf(acc.x) | ((unsigned)(unsigned short)f2bf(acc.y) << 16);
    unsigned hi = (unsigned)(unsigned short)f2bf(acc.z) | ((unsigned)(unsigned short)f2bf(acc.w) << 16);
    uint2 pk = {lo, hi};
    *(uint2*)(ctxbf + (size_t)row * D_ + lane * 4) = pk;
}

// ---------------------------------------------------------------------------
// FUSED GEMM + bias + bf16-residual + LayerNorm. BM=16, BN=256, grid M/16.
// res is bf16. WF32: write fp32 out; WBF: write bf16 out.
// ---------------------------------------------------------------------------
template<int KD, int WF32, int WBF>
__global__ __launch_bounds__(256) void gemm_ln_mfma(
    const short* __restrict__ A, const short* __restrict__ W,
    const float* __restrict__ bias, const short* __restrict__ resbf,
    const float* __restrict__ g, const float* __restrict__ beta,
    float* __restrict__ outf, short* __restrict__ outbf)
{
    __shared__ short As[2][16 * 32];
    __shared__ short Bs[2][256 * 32];
    __shared__ float part[4][16][2];

    const int tid  = threadIdx.x;
    const int wave = tid >> 6;
    const int lane = tid & 63;
    const int bm = blockIdx.x * 16;
    const int wc = wave * 64;
    const int fr = lane & 15;
    const int fk = (lane >> 4) * 8;
    const int r0 = tid >> 2, ch = (tid & 3) * 8;

    f32x4 acc[4];
    #pragma unroll
    for (int j = 0; j < 4; ++j) acc[j] = (f32x4){0.f, 0.f, 0.f, 0.f};

    auto stage = [&](int buf, int k0) {
        if (tid < 64)
            __builtin_amdgcn_global_load_lds(
                (ga_int*)&A[(size_t)(bm + r0) * KD + k0 + ch],
                (ls_int*)&As[buf][tid * 8], 16, 0, 0);
        #pragma unroll
        for (int j = 0; j < 4; ++j)
            __builtin_amdgcn_global_load_lds(
                (ga_int*)&W[(size_t)(r0 + j * 64) * KD + k0 + ch],
                (ls_int*)&Bs[buf][(tid + j * 256) * 8], 16, 0, 0);
    };

    stage(0, 0);
    int cur = 0;

    for (int k0 = 0; k0 < KD; k0 += 32) {
        __syncthreads();
        if (k0 + 32 < KD) stage(cur ^ 1, k0 + 32);

        bf16x8 af = *(bf16x8*)&As[cur][fr * 32 + fk];
        bf16x8 bfr[4];
        #pragma unroll
        for (int j = 0; j < 4; ++j) bfr[j] = *(bf16x8*)&Bs[cur][(wc + j * 16 + fr) * 32 + fk];
        #pragma unroll
        for (int j = 0; j < 4; ++j)
            acc[j] = __builtin_amdgcn_mfma_f32_16x16x32_bf16(af, bfr[j], acc[j], 0, 0, 0);
        cur ^= 1;
    }

    const int rowbase = (lane >> 4) * 4;
    float vv[4][4];
    float sum[4] = {0.f, 0.f, 0.f, 0.f};
    float sq[4]  = {0.f, 0.f, 0.f, 0.f};

    #pragma unroll
    for (int j = 0; j < 4; ++j) {
        const int n = wc + j * 16 + fr;
        const float bv = bias[n];
        #pragma unroll
        for (int r = 0; r < 4; ++r) {
            const int m = bm + rowbase + r;
            float v = acc[j][r] + bv + bf2f(resbf[(size_t)m * D_ + n]);
            vv[j][r] = v;
            sum[r] += v;
            sq[r]  += v * v;
        }
    }

    #pragma unroll
    for (int r = 0; r < 4; ++r)
        #pragma unroll
        for (int s = 1; s < 16; s <<= 1) {
            sum[r] += __shfl_xor(sum[r], s, 64);
            sq[r]  += __shfl_xor(sq[r],  s, 64);
        }

    if (fr == 0) {
        #pragma unroll
        for (int r = 0; r < 4; ++r) {
            part[wave][rowbase + r][0] = sum[r];
            part[wave][rowbase + r][1] = sq[r];
        }
    }
    __syncthreads();

    #pragma unroll
    for (int r = 0; r < 4; ++r) {
        const int ml = rowbase + r;
        const float S = part[0][ml][0] + part[1][ml][0] + part[2][ml][0] + part[3][ml][0];
        const float Q = part[0][ml][1] + part[1][ml][1] + part[2][ml][1] + part[3][ml][1];
        const float mean = S * (1.0f / D_);
        const float var  = Q * (1.0f / D_) - mean * mean;
        const float rstd = rsqrtf(var + 1e-5f);
        const int m = bm + ml;
        #pragma unroll
        for (int j = 0; j < 4; ++j) {
            const int n = wc + j * 16 + fr;
            float o = (vv[j][r] - mean) * rstd * g[n] + beta[n];
            if (WF32) outf[(size_t)m * D_ + n] = o;
            if (WBF)  outbf[(size_t)m * D_ + n] = f2bf(o);
        }
    }
}

// ---------------------------------------------------------------------------
extern "C" void kernel_launch(void* const* d_in, const int* in_sizes, int n_in,
                              void* d_out, int out_size, void* d_ws, size_t ws_size,
                              hipStream_t stream)
{
    const float* x      = (const float*)d_in[0];
    const float* wq_rec = (const float*)d_in[1];
    const float* wk_rec = (const float*)d_in[2];
    const float* in_w   = (const float*)d_in[3];
    const float* in_b   = (const float*)d_in[4];
    const float* out_w  = (const float*)d_in[5];
    const float* out_b  = (const float*)d_in[6];
    const float* ln1_g  = (const float*)d_in[7];
    const float* ln1_b  = (const float*)d_in[8];
    const float* w1     = (const float*)d_in[9];
    const float* b1     = (const float*)d_in[10];
    const float* w2     = (const float*)d_in[11];
    const float* b2     = (const float*)d_in[12];
    const float* ln2_g  = (const float*)d_in[13];
    const float* ln2_b  = (const float*)d_in[14];
    float* out = (float*)d_out;

    // ---- workspace layout ----
    short* qkvbf = (short*)d_ws;                    // M*768 sh (bf16 q|k|v)
    short* qh    = qkvbf + (size_t)M_ * 768;        // M*128 sh
    short* ql    = qh + (size_t)M_ * RD_;
    short* kh    = ql + (size_t)M_ * RD_;
    short* kl    = kh + (size_t)M_ * RD_;
    float* U     = (float*)(kl + (size_t)M_ * RD_);
    float* logits = U;                                  // M*512 f
    short* ctxbf  = (short*)(U + (size_t)M_ * 512);     // M*256 sh
    short* x1bf   = ctxbf + (size_t)M_ * D_;            // M*256 sh
    short* hbf    = x1bf  + (size_t)M_ * D_;            // M*1024 sh
    short* xbf    = hbf   + (size_t)M_ * FFN_;          // M*256 sh
    short* xlo    = xbf   + (size_t)M_ * D_;
    short* inwbf  = xlo   + (size_t)M_ * D_;
    short* outwbf = inwbf + (size_t)768 * D_;
    short* w1bf   = outwbf + (size_t)D_ * D_;
    short* w2bf   = w1bf  + (size_t)FFN_ * D_;
    short* wqh    = w2bf  + (size_t)D_ * FFN_;
    short* wql    = wqh + (size_t)RD_ * D_;
    short* wkh    = wql + (size_t)RD_ * D_;
    short* wkl    = wkh + (size_t)RD_ * D_;

    dim3 blk(256);

    // 0) all bf16 conversions (+ hi/lo splits), one launch
    convert_all_kernel<<<dim3((N8_ALL + 255) / 256), blk, 0, stream>>>(
        x, in_w, out_w, w1, w2, wq_rec, wk_rec,
        xbf, xlo, inwbf, outwbf, w1bf, w2bf, wqh, wql, wkh, wkl);

    // 1) merged qkv + xq/xk projections (1280 blocks)
    proj_kernel<<<dim3(1280), blk, 0, stream>>>(
        xbf, xlo, inwbf, in_b, wqh, wql, wkh, wkl, qkvbf, qh, ql, kh, kl);
    // 2) logits, split-bf16 MFMA (1024 blocks)
    logits_mfma<<<dim3(C_ / 64, C_ / 64, B_), blk, 0, stream>>>(qh, ql, kh, kl, logits);
    // 3) fused top-16 + gathered attention -> ctx (bf16)
    topk_attn_kernel<<<dim3(M_ / 4), blk, 0, stream>>>(logits, qkvbf, ctxbf);
    // 4) out projection + bf16-residual(x) + LN1 -> x1bf only (512 blocks)
    gemm_ln_mfma<256, 0, 1><<<dim3(M_ / 16), blk, 0, stream>>>(
        ctxbf, outwbf, out_b, xbf, ln1_g, ln1_b, nullptr, x1bf);
    // 5) h = gelu(x1 @ w1^T + b1) (MFMA, 64x128 -> 1024 blocks, bf16 out)
    gemm_mfma<64, 128, 1, 1><<<dim3(FFN_ / 128, M_ / 64), blk, 0, stream>>>(x1bf, w1bf, b1, hbf, M_, FFN_, D_);
    // 6) y = h @ w2^T + b2 + bf16-residual(x1) + LN2 -> out fp32 (512 blocks)
    gemm_ln_mfma<1024, 1, 0><<<dim3(M_ / 16), blk, 0, stream>>>(
        hbf, w2bf, b2, x1bf, ln2_g, ln2_b, out, nullptr);
}